// Round 7
// baseline (1434.403 us; speedup 1.0000x reference)
//
#include <hip/hip_runtime.h>
#include <hip/hip_bf16.h>
#include <math.h>

#define GN 19            // graph nodes
#define BB 256
#define TT 256

typedef short short8 __attribute__((ext_vector_type(8)));
typedef float f4 __attribute__((ext_vector_type(4)));
typedef unsigned short u16;

union Frag { int i[4]; short8 s; };

// wave-local LDS ordering fence: wait LDS ops, NO vmcnt drain, no barrier.
#define LWAIT() __asm__ volatile("s_waitcnt lgkmcnt(0)" ::: "memory")
// workgroup barrier WITHOUT vmcnt(0) drain: global loads stay in flight.
#define WGBAR() __asm__ volatile("s_waitcnt lgkmcnt(0)\ns_barrier" ::: "memory")
// opaque-register pin
#define PIN8(x) __asm__ volatile("" : "+v"(x))
#define PINF(x) __asm__ volatile("" : "+v"(x))

#define MFMA(a,b,c) __builtin_amdgcn_mfma_f32_16x16x32_bf16(a,b,c,0,0,0)

// packed RNE float pair -> bf16 pair (v_cvt_pk_bf16_f32 on gfx950)
__device__ __forceinline__ int pkbf(float a, float b) {
    __hip_bfloat162 h2 = __float22bfloat162_rn(make_float2(a, b));
    union { __hip_bfloat162 h; int i; } u; u.h = h2; return u.i;
}

__device__ __forceinline__ float fexp2(float x) { return __builtin_amdgcn_exp2f(x); }
__device__ __forceinline__ float frcp(float x)  { return __builtin_amdgcn_rcpf(x); }
__device__ __forceinline__ float sigm(float x)  { return frcp(1.f + fexp2(-1.4426950408889634f * x)); }
__device__ __forceinline__ float tanha(float x) { float e = fexp2(2.8853900817779268f * x); return 1.f - 2.f * frcp(e + 1.f); }

// ---------------------------------------------------------------------------
// Kernel A: graph encoder via bf16 MFMA (16x16x32).  UNCHANGED.
// ---------------------------------------------------------------------------
__global__ __launch_bounds__(64) void encoder_mfma(
    const float* __restrict__ conn,   // (G,19,19)
    const int*   __restrict__ mask,   // (G)
    const float* __restrict__ w1_w,   // (64,19)
    const float* __restrict__ w1_b,   // (64)
    const float* __restrict__ w2_w,   // (64,64)
    const float* __restrict__ w2_b,   // (64)
    u16* __restrict__ emb,            // (G,64) bf16
    int num_graphs)
{
    __shared__ float S[2304];         // 9216 B, reused 4 ways
    __shared__ float dis[32];
    __shared__ float ps[256];

    const int t = threadIdx.x;
    const int l15 = t & 15;
    const int quad = t >> 4;

    float km[8];
    #pragma unroll
    for (int j = 0; j < 8; ++j) km[j] = (quad * 8 + j < GN) ? 1.f : 0.f;

    int rr[6], cc[6];
    #pragma unroll
    for (int i = 0; i < 6; ++i) {
        int e = t + 64 * i;
        rr[i] = e / GN;
        cc[i] = e - rr[i] * GN;
    }

    Frag w1F[4];
    #pragma unroll
    for (int nt = 0; nt < 4; ++nt) {
        int n = nt * 16 + l15;
        #pragma unroll
        for (int p = 0; p < 4; ++p) {
            int k0 = quad * 8 + 2 * p, k1 = k0 + 1;
            float a = (k0 < GN) ? w1_w[n * GN + k0] : 0.f;
            float b = (k1 < GN) ? w1_w[n * GN + k1] : 0.f;
            w1F[nt].i[p] = pkbf(a, b);
        }
    }
    Frag w2F[2][4];
    #pragma unroll
    for (int kt = 0; kt < 2; ++kt)
        #pragma unroll
        for (int nt = 0; nt < 4; ++nt) {
            int n = nt * 16 + l15;
            #pragma unroll
            for (int p = 0; p < 4; ++p) {
                int k = kt * 32 + quad * 8 + 2 * p;
                w2F[kt][nt].i[p] = pkbf(w2_w[n * 64 + k], w2_w[n * 64 + k + 1]);
            }
        }
    float b1v[4], b2v[4];
    #pragma unroll
    for (int nt = 0; nt < 4; ++nt) {
        b1v[nt] = w1_b[nt * 16 + l15];
        b2v[nt] = w2_b[nt * 16 + l15];
    }

    float pf[6];
    {
        int g0 = blockIdx.x < num_graphs ? blockIdx.x : 0;
        const float* Ag = conn + (size_t)g0 * (GN * GN);
        #pragma unroll
        for (int i = 0; i < 6; ++i) {
            int e = t + 64 * i;
            if (e < GN * GN) pf[i] = Ag[e];
        }
    }

    #pragma unroll 1
    for (int g = blockIdx.x; g < num_graphs; g += gridDim.x) {
        #pragma unroll
        for (int i = 0; i < 4; ++i) {
            int s = t + 64 * i;
            int row = s >> 3, c4 = s & 7;
            f4 z = {0.f, 0.f, 0.f, 0.f};
            *(f4*)&S[row * 68 + c4 * 4] = z;
        }
        LWAIT();
        #pragma unroll
        for (int i = 0; i < 6; ++i) {
            if (t + 64 * i < GN * GN) S[rr[i] * 68 + cc[i]] = pf[i];
        }
        {
            int gn = g + gridDim.x;
            const float* Ag = conn + (size_t)(gn < num_graphs ? gn : g) * (GN * GN);
            #pragma unroll
            for (int i = 0; i < 6; ++i) {
                int e = t + 64 * i;
                if (e < GN * GN) pf[i] = Ag[e];
            }
        }
        LWAIT();

        if (t < 32) {
            float dv = 0.f;
            if (t < GN) {
                float d = 1.0f;
                #pragma unroll
                for (int c4 = 0; c4 < 8; ++c4) {
                    f4 v = *(f4*)&S[t * 68 + c4 * 4];
                    d += v.x + v.y + v.z + v.w;
                }
                dv = rsqrtf(d);
            }
            dis[t] = dv;
        }
        LWAIT();

        float dk[8];
        {
            f4 v0 = *(f4*)&dis[quad * 8];
            f4 v1 = *(f4*)&dis[quad * 8 + 4];
            dk[0]=v0.x; dk[1]=v0.y; dk[2]=v0.z; dk[3]=v0.w;
            dk[4]=v1.x; dk[5]=v1.y; dk[6]=v1.z; dk[7]=v1.w;
        }
        Frag aF[2], anF[2];
        #pragma unroll
        for (int mt = 0; mt < 2; ++mt) {
            int m = l15 + 16 * mt;
            float dm = dis[m];
            f4 v0 = *(f4*)&S[m * 68 + quad * 8];
            f4 v1 = *(f4*)&S[m * 68 + quad * 8 + 4];
            float av[8] = {v0.x, v0.y, v0.z, v0.w, v1.x, v1.y, v1.z, v1.w};
            float an[8];
            #pragma unroll
            for (int j = 0; j < 8; ++j) {
                int k = quad * 8 + j;
                an[j] = (av[j] + (m == k ? 1.f : 0.f)) * dm * dk[j];
            }
            #pragma unroll
            for (int p = 0; p < 4; ++p) {
                aF[mt].i[p]  = pkbf(av[2*p], av[2*p+1]);
                anF[mt].i[p] = pkbf(an[2*p], an[2*p+1]);
            }
        }
        LWAIT();

        #pragma unroll
        for (int mt = 0; mt < 2; ++mt)
            #pragma unroll
            for (int nt = 0; nt < 4; ++nt) {
                float bb = b1v[nt];
                f4 c = {bb, bb, bb, bb};
                c = MFMA(aF[mt].s, w1F[nt].s, c);
                int col = nt * 16 + l15;
                #pragma unroll
                for (int r = 0; r < 4; ++r)
                    S[col * 36 + (mt * 16 + quad * 4 + r)] = c[r];
            }
        LWAIT();

        Frag hF[4];
        #pragma unroll
        for (int nt = 0; nt < 4; ++nt) {
            int n = nt * 16 + l15;
            f4 v0 = *(f4*)&S[n * 36 + quad * 8];
            f4 v1 = *(f4*)&S[n * 36 + quad * 8 + 4];
            float vv[8] = {v0.x, v0.y, v0.z, v0.w, v1.x, v1.y, v1.z, v1.w};
            #pragma unroll
            for (int p = 0; p < 4; ++p)
                hF[nt].i[p] = pkbf(vv[2*p] * km[2*p], vv[2*p+1] * km[2*p+1]);
        }
        LWAIT();

        #pragma unroll
        for (int mt = 0; mt < 2; ++mt)
            #pragma unroll
            for (int nt = 0; nt < 4; ++nt) {
                f4 c = {0.f, 0.f, 0.f, 0.f};
                c = MFMA(anF[mt].s, hF[nt].s, c);
                int col = nt * 16 + l15;
                #pragma unroll
                for (int r = 0; r < 4; ++r)
                    S[(mt * 16 + quad * 4 + r) * 68 + col] = fmaxf(c[r], 0.f);
            }
        LWAIT();

        Frag xF[2][2];
        #pragma unroll
        for (int mt = 0; mt < 2; ++mt) {
            int m = l15 + 16 * mt;
            #pragma unroll
            for (int kt = 0; kt < 2; ++kt) {
                f4 v0 = *(f4*)&S[m * 68 + kt * 32 + quad * 8];
                f4 v1 = *(f4*)&S[m * 68 + kt * 32 + quad * 8 + 4];
                xF[mt][kt].i[0] = pkbf(v0.x, v0.y);
                xF[mt][kt].i[1] = pkbf(v0.z, v0.w);
                xF[mt][kt].i[2] = pkbf(v1.x, v1.y);
                xF[mt][kt].i[3] = pkbf(v1.z, v1.w);
            }
        }
        LWAIT();

        #pragma unroll
        for (int mt = 0; mt < 2; ++mt)
            #pragma unroll
            for (int nt = 0; nt < 4; ++nt) {
                float bb = b2v[nt];
                f4 c = {bb, bb, bb, bb};
                c = MFMA(xF[mt][0].s, w2F[0][nt].s, c);
                c = MFMA(xF[mt][1].s, w2F[1][nt].s, c);
                int col = nt * 16 + l15;
                #pragma unroll
                for (int r = 0; r < 4; ++r)
                    S[col * 36 + (mt * 16 + quad * 4 + r)] = c[r];
            }
        LWAIT();

        Frag hG[4];
        #pragma unroll
        for (int nt = 0; nt < 4; ++nt) {
            int n = nt * 16 + l15;
            f4 v0 = *(f4*)&S[n * 36 + quad * 8];
            f4 v1 = *(f4*)&S[n * 36 + quad * 8 + 4];
            float vv[8] = {v0.x, v0.y, v0.z, v0.w, v1.x, v1.y, v1.z, v1.w};
            #pragma unroll
            for (int p = 0; p < 4; ++p)
                hG[nt].i[p] = pkbf(vv[2*p] * km[2*p], vv[2*p+1] * km[2*p+1]);
        }

        float cs[4];
        #pragma unroll
        for (int nt = 0; nt < 4; ++nt) cs[nt] = 0.f;
        #pragma unroll
        for (int mt = 0; mt < 2; ++mt)
            #pragma unroll
            for (int nt = 0; nt < 4; ++nt) {
                f4 c = {0.f, 0.f, 0.f, 0.f};
                c = MFMA(anF[mt].s, hG[nt].s, c);
                if (mt == 0) {
                    cs[nt] += fmaxf(c[0], 0.f) + fmaxf(c[1], 0.f)
                            + fmaxf(c[2], 0.f) + fmaxf(c[3], 0.f);
                } else if (quad == 0) {
                    cs[nt] += fmaxf(c[0], 0.f) + fmaxf(c[1], 0.f) + fmaxf(c[2], 0.f);
                }
            }
        #pragma unroll
        for (int nt = 0; nt < 4; ++nt)
            ps[quad * 64 + nt * 16 + l15] = cs[nt];
        LWAIT();
        float tot = ps[t] + ps[64 + t] + ps[128 + t] + ps[192 + t];
        float mf = (float)mask[g];
        float v = tot * (1.f / 19.f) * mf;
        emb[(size_t)g * 64 + t] = (u16)(unsigned)pkbf(v, v);  // low16 = bf16RNE(v)
        LWAIT();
    }
}

// read single-bf16 h B-fragments straight from LDS (zero VALU)
__device__ __forceinline__ void read_h1(const u16* __restrict__ hs,
                                        int off, Frag* __restrict__ BH)
{
    #pragma unroll
    for (int kt = 0; kt < 2; ++kt) {
        int4 vh = *(const int4*)&hs[off + kt * 32];
        BH[kt].i[0] = vh.x; BH[kt].i[1] = vh.y;
        BH[kt].i[2] = vh.z; BH[kt].i[3] = vh.w;
    }
}

// ---------------------------------------------------------------------------
// Kernel B v7: TWO independent batch-16 LSTM groups per 1024-thread block.
// R5's post-mortem: step ~2430 cyc vs ~500 cyc critical path -> ~80% stall,
// because every wave on the CU belongs to ONE block that locksteps at the
// same barrier: nothing independent is resident to absorb chain latency.
// The dispatcher won't co-place two 512-thread blocks on one CU (16 blocks
// scatter over 256 CUs), so co-residency is done MANUALLY:
//   8 blocks x 1024 threads = 16 waves = 2 independent groups of 8 waves;
//   group bg handles batches [blk*32 + bg*16, +16).  Groups share the
//   per-step s_barrier, but between barriers the two groups' MFMA + act
//   chains interleave on the 4 SIMDs (4 waves/SIMD) -> group A's stalls
//   fill with group B's issue.  Per-wave structure identical to R5.
// waves_per_eu(4,4): 128-VGPR budget >= the 88 the R5 kernel allocates.
// ---------------------------------------------------------------------------
__global__ __launch_bounds__(1024) __attribute__((amdgpu_waves_per_eu(4, 4)))
void lstm_mfma(
    const u16*   __restrict__ x,      // (B*T, 64) bf16 = emb
    const int*   __restrict__ mask,   // (B, T)
    const float* __restrict__ Wih0, const float* __restrict__ Whh0,
    const float* __restrict__ bih0, const float* __restrict__ bhh0,
    const float* __restrict__ Wih1, const float* __restrict__ Whh1,
    const float* __restrict__ bih1, const float* __restrict__ bhh1,
    const float* __restrict__ fc1_w, const float* __restrict__ fc1_b,
    const float* __restrict__ fc2_w, const float* __restrict__ fc2_b,
    float* __restrict__ out)          // (B, 2)
{
    __shared__ __attribute__((aligned(16))) u16 h0s[2][2][16 * 72]; // [bg][dbuf]
    __shared__ __attribute__((aligned(16))) u16 h1s[2][2][16 * 72];
    __shared__ float hlast[32][68];
    __shared__ float red[1024];
    __shared__ int   li_s[32];

    const int tid  = threadIdx.x;     // 0..1023
    const int w    = tid >> 6;        // wave 0..15
    const int bg   = w >> 3;          // batch-group 0/1
    const int wv   = w & 7;           // wave within group
    const int grp  = wv >> 2;         // 0: layer 0, 1: layer 1
    const int wl   = wv & 3;          // wave within layer
    const int lane = tid & 63;
    const int l15  = lane & 15;       // batch col within group
    const int quad = lane >> 4;
    const int bb0  = blockIdx.x * 32 + bg * 16;

    // zero h1 dbuf[0] for both groups (read as h1(-1)=0 after it=0's barrier)
    for (int i = tid; i < 2 * 16 * 72; i += 1024) h1s[i / (16 * 72)][0][i % (16 * 72)] = 0;

    // ---- lastidx per batch row (32 rows) ----
    {
        int b32 = tid >> 5, j = tid & 31;
        int s = 0;
        #pragma unroll
        for (int c8 = 0; c8 < 8; ++c8)
            s += mask[(blockIdx.x * 32 + b32) * TT + j + 32 * c8];
        red[tid] = (float)s;
    }
    __syncthreads();
    if (tid < 32) {
        float s = 0.f;
        #pragma unroll
        for (int j = 0; j < 32; ++j) s += red[tid * 32 + j];
        int li = (int)s - 1;
        li_s[tid] = li < 0 ? 0 : (li > TT - 1 ? TT - 1 : li);
    }
    __syncthreads();
    const int li = li_s[bg * 16 + l15];

    // ---- this wave's layer weights: 4 gate-tiles, 16 frags ----
    const float* __restrict__ Wx = grp ? Wih1 : Wih0;
    const float* __restrict__ Wh = grp ? Whh1 : Whh0;
    const float* __restrict__ bi = grp ? bih1 : bih0;
    const float* __restrict__ bh = grp ? bhh1 : bhh0;

    Frag Ax[4][2], Ah[4][2];
    f4 biasv[4];
    #pragma unroll
    for (int mt = 0; mt < 4; ++mt) {
        int mg = 4 * wl + mt;
        int orig = (l15 & 3) * 64 + (mg * 4 + (l15 >> 2));
        #pragma unroll
        for (int kt = 0; kt < 2; ++kt)
            #pragma unroll
            for (int p = 0; p < 4; ++p) {
                int k = kt * 32 + quad * 8 + 2 * p;
                Ax[mt][kt].i[p] = pkbf(Wx[orig * 64 + k], Wx[orig * 64 + k + 1]);
                Ah[mt][kt].i[p] = pkbf(Wh[orig * 64 + k], Wh[orig * 64 + k + 1]);
            }
        int uu = mg * 4 + quad;
        #pragma unroll
        for (int r = 0; r < 4; ++r)
            biasv[mt][r] = bi[r * 64 + uu] + bh[r * 64 + uu];
    }
    #pragma unroll
    for (int mt = 0; mt < 4; ++mt) {
        PIN8(Ax[mt][0].s); PIN8(Ax[mt][1].s);
        PIN8(Ah[mt][0].s); PIN8(Ah[mt][1].s);
        PINF(biasv[mt]);
    }

    // unit owned by (mt, quad): 16*wl + 4*mt + quad
    const int ubase = 16 * wl + quad;
    const int hoff = l15 * 72 + quad * 8;   // B-frag read base

    // ---- state ----
    Frag BH0[2], BH1[2], BXn[2];
    #pragma unroll
    for (int kt = 0; kt < 2; ++kt)
        #pragma unroll
        for (int p = 0; p < 4; ++p) {
            BXn[kt].i[p] = 0; BH0[kt].i[p] = 0; BH1[kt].i[p] = 0;
        }
    float cst[4] = {0.f, 0.f, 0.f, 0.f};
    float hlv[4] = {0.f, 0.f, 0.f, 0.f};

    const u16* __restrict__ xb = x + (size_t)(bb0 + l15) * TT * 64;
    if (grp == 0) {
        BXn[0] = *(const Frag*)&xb[quad * 8];
        BXn[1] = *(const Frag*)&xb[32 + quad * 8];
    }

    // iteration it: layer 0 does step it; layer 1 does step it-1.
    #pragma unroll 1
    for (int it = 0; it <= TT; ++it) {
        const int cur = it & 1;
        f4 g[4];
        bool act = false;

        if (grp == 0) {
            if (it < TT) {
                act = true;
                Frag bx0 = BXn[0], bx1 = BXn[1];
                int tn = it + 1 < TT ? it + 1 : TT - 1;
                BXn[0] = *(const Frag*)&xb[(size_t)tn * 64 + quad * 8];
                BXn[1] = *(const Frag*)&xb[(size_t)tn * 64 + 32 + quad * 8];

                #pragma unroll
                for (int mt = 0; mt < 4; ++mt) {
                    // two chains of depth 2; x-MFMA first (independent of h)
                    f4 ca = biasv[mt];
                    ca = MFMA(Ax[mt][0].s, bx0.s,    ca);
                    ca = MFMA(Ah[mt][0].s, BH0[0].s, ca);
                    f4 cb = {0.f, 0.f, 0.f, 0.f};
                    cb = MFMA(Ax[mt][1].s, bx1.s,    cb);
                    cb = MFMA(Ah[mt][1].s, BH0[1].s, cb);
                    g[mt] = ca + cb;
                }
            }
        } else {
            if (it >= 1) {
                act = true;
                #pragma unroll
                for (int mt = 0; mt < 4; ++mt) {
                    f4 ca = biasv[mt];
                    ca = MFMA(Ax[mt][0].s, BH0[0].s, ca);
                    ca = MFMA(Ah[mt][0].s, BH1[0].s, ca);
                    f4 cb = {0.f, 0.f, 0.f, 0.f};
                    cb = MFMA(Ax[mt][1].s, BH0[1].s, cb);
                    cb = MFMA(Ah[mt][1].s, BH1[1].s, cb);
                    g[mt] = ca + cb;
                }
            }
        }

        if (act) {
            u16* __restrict__ dst = grp ? h1s[bg][cur] : h0s[bg][cur];
            #pragma unroll
            for (int mt = 0; mt < 4; ++mt) {
                f4 gg = g[mt];
                float si = sigm(gg[0]), sf = sigm(gg[1]);
                float tg = tanha(gg[2]), so = sigm(gg[3]);
                float cc = fmaf(sf, cst[mt], si * tg);
                cst[mt] = cc;
                float h = so * tanha(cc);
                if (grp && it - 1 == li) hlv[mt] = h;
                dst[l15 * 72 + ubase + 4 * mt] = (u16)(unsigned)pkbf(h, h);
            }
        }

        WGBAR();   // lgkmcnt(0)+s_barrier; X prefetch stays in flight

        if (it < TT) {
            read_h1(h0s[bg][cur], hoff, BH0);
            if (grp) read_h1(h1s[bg][cur], hoff, BH1);
        }
    }

    // ---- head (32 batch rows) ----
    if (grp == 1) {
        #pragma unroll
        for (int mt = 0; mt < 4; ++mt)
            hlast[bg * 16 + l15][ubase + 4 * mt] = hlv[mt];
    }
    __syncthreads();
    {
        int b = tid >> 5, o = tid & 31;
        float acc = fc1_b[o];
        const float* fw = fc1_w + o * 64;
        #pragma unroll
        for (int j = 0; j < 64; ++j)
            acc = fmaf(hlast[b][j], fw[j], acc);
        red[b * 32 + o] = fmaxf(acc, 0.f);
    }
    __syncthreads();
    if (tid < 64) {
        int b = tid >> 1, o = tid & 1;
        float acc = fc2_b[o];
        #pragma unroll
        for (int j = 0; j < 32; ++j)
            acc = fmaf(fc2_w[o * 32 + j], red[b * 32 + j], acc);
        out[(blockIdx.x * 32 + b) * 2 + o] = acc;
    }
}

// ---------------------------------------------------------------------------
extern "C" void kernel_launch(void* const* d_in, const int* in_sizes, int n_in,
                              void* d_out, int out_size, void* d_ws, size_t ws_size,
                              hipStream_t stream)
{
    const float* conn  = (const float*)d_in[0];
    const int*   mask  = (const int*)  d_in[1];
    const float* w1_w  = (const float*)d_in[2];
    const float* w1_b  = (const float*)d_in[3];
    const float* w2_w  = (const float*)d_in[4];
    const float* w2_b  = (const float*)d_in[5];
    const float* Wih0  = (const float*)d_in[6];
    const float* Whh0  = (const float*)d_in[7];
    const float* bih0  = (const float*)d_in[8];
    const float* bhh0  = (const float*)d_in[9];
    const float* Wih1  = (const float*)d_in[10];
    const float* Whh1  = (const float*)d_in[11];
    const float* bih1  = (const float*)d_in[12];
    const float* bhh1  = (const float*)d_in[13];
    const float* fc1_w = (const float*)d_in[14];
    const float* fc1_b = (const float*)d_in[15];
    const float* fc2_w = (const float*)d_in[16];
    const float* fc2_b = (const float*)d_in[17];

    float* out = (float*)d_out;
    u16*   emb = (u16*)d_ws;          // 8.4 MB bf16

    const int num_graphs = BB * TT;

    encoder_mfma<<<8192, 64, 0, stream>>>(
        conn, mask, w1_w, w1_b, w2_w, w2_b, emb, num_graphs);

    lstm_mfma<<<8, 1024, 0, stream>>>(
        emb, mask, Wih0, Whh0, bih0, bhh0, Wih1, Whh1, bih1, bhh1,
        fc1_w, fc1_b, fc2_w, fc2_b, out);
}

// Round 8
// 738.723 us; speedup vs baseline: 1.9417x; 1.9417x over previous
//
#include <hip/hip_runtime.h>
#include <hip/hip_bf16.h>
#include <math.h>

#define GN 19            // graph nodes
#define BB 256
#define TT 256

typedef short short8 __attribute__((ext_vector_type(8)));
typedef float f4 __attribute__((ext_vector_type(4)));
typedef unsigned short u16;

union Frag { int i[4]; short8 s; };

// wave-local LDS ordering fence: wait LDS ops, NO vmcnt drain, no barrier.
#define LWAIT() __asm__ volatile("s_waitcnt lgkmcnt(0)" ::: "memory")
// workgroup barrier WITHOUT vmcnt(0) drain: global loads stay in flight.
#define WGBAR() __asm__ volatile("s_waitcnt lgkmcnt(0)\ns_barrier" ::: "memory")
// opaque-register pin
#define PIN8(x) __asm__ volatile("" : "+v"(x))
#define PINF(x) __asm__ volatile("" : "+v"(x))

#define MFMA(a,b,c) __builtin_amdgcn_mfma_f32_16x16x32_bf16(a,b,c,0,0,0)

// packed RNE float pair -> bf16 pair (v_cvt_pk_bf16_f32 on gfx950)
__device__ __forceinline__ int pkbf(float a, float b) {
    __hip_bfloat162 h2 = __float22bfloat162_rn(make_float2(a, b));
    union { __hip_bfloat162 h; int i; } u; u.h = h2; return u.i;
}

__device__ __forceinline__ float fexp2(float x) { return __builtin_amdgcn_exp2f(x); }
__device__ __forceinline__ float frcp(float x)  { return __builtin_amdgcn_rcpf(x); }
__device__ __forceinline__ float sigm(float x)  { return frcp(1.f + fexp2(-1.4426950408889634f * x)); }
__device__ __forceinline__ float tanha(float x) { float e = fexp2(2.8853900817779268f * x); return 1.f - 2.f * frcp(e + 1.f); }

// ---------------------------------------------------------------------------
// Kernel A: graph encoder via bf16 MFMA (16x16x32).  UNCHANGED.
// ---------------------------------------------------------------------------
__global__ __launch_bounds__(64) void encoder_mfma(
    const float* __restrict__ conn,   // (G,19,19)
    const int*   __restrict__ mask,   // (G)
    const float* __restrict__ w1_w,   // (64,19)
    const float* __restrict__ w1_b,   // (64)
    const float* __restrict__ w2_w,   // (64,64)
    const float* __restrict__ w2_b,   // (64)
    u16* __restrict__ emb,            // (G,64) bf16
    int num_graphs)
{
    __shared__ float S[2304];         // 9216 B, reused 4 ways
    __shared__ float dis[32];
    __shared__ float ps[256];

    const int t = threadIdx.x;
    const int l15 = t & 15;
    const int quad = t >> 4;

    float km[8];
    #pragma unroll
    for (int j = 0; j < 8; ++j) km[j] = (quad * 8 + j < GN) ? 1.f : 0.f;

    int rr[6], cc[6];
    #pragma unroll
    for (int i = 0; i < 6; ++i) {
        int e = t + 64 * i;
        rr[i] = e / GN;
        cc[i] = e - rr[i] * GN;
    }

    Frag w1F[4];
    #pragma unroll
    for (int nt = 0; nt < 4; ++nt) {
        int n = nt * 16 + l15;
        #pragma unroll
        for (int p = 0; p < 4; ++p) {
            int k0 = quad * 8 + 2 * p, k1 = k0 + 1;
            float a = (k0 < GN) ? w1_w[n * GN + k0] : 0.f;
            float b = (k1 < GN) ? w1_w[n * GN + k1] : 0.f;
            w1F[nt].i[p] = pkbf(a, b);
        }
    }
    Frag w2F[2][4];
    #pragma unroll
    for (int kt = 0; kt < 2; ++kt)
        #pragma unroll
        for (int nt = 0; nt < 4; ++nt) {
            int n = nt * 16 + l15;
            #pragma unroll
            for (int p = 0; p < 4; ++p) {
                int k = kt * 32 + quad * 8 + 2 * p;
                w2F[kt][nt].i[p] = pkbf(w2_w[n * 64 + k], w2_w[n * 64 + k + 1]);
            }
        }
    float b1v[4], b2v[4];
    #pragma unroll
    for (int nt = 0; nt < 4; ++nt) {
        b1v[nt] = w1_b[nt * 16 + l15];
        b2v[nt] = w2_b[nt * 16 + l15];
    }

    float pf[6];
    {
        int g0 = blockIdx.x < num_graphs ? blockIdx.x : 0;
        const float* Ag = conn + (size_t)g0 * (GN * GN);
        #pragma unroll
        for (int i = 0; i < 6; ++i) {
            int e = t + 64 * i;
            if (e < GN * GN) pf[i] = Ag[e];
        }
    }

    #pragma unroll 1
    for (int g = blockIdx.x; g < num_graphs; g += gridDim.x) {
        #pragma unroll
        for (int i = 0; i < 4; ++i) {
            int s = t + 64 * i;
            int row = s >> 3, c4 = s & 7;
            f4 z = {0.f, 0.f, 0.f, 0.f};
            *(f4*)&S[row * 68 + c4 * 4] = z;
        }
        LWAIT();
        #pragma unroll
        for (int i = 0; i < 6; ++i) {
            if (t + 64 * i < GN * GN) S[rr[i] * 68 + cc[i]] = pf[i];
        }
        {
            int gn = g + gridDim.x;
            const float* Ag = conn + (size_t)(gn < num_graphs ? gn : g) * (GN * GN);
            #pragma unroll
            for (int i = 0; i < 6; ++i) {
                int e = t + 64 * i;
                if (e < GN * GN) pf[i] = Ag[e];
            }
        }
        LWAIT();

        if (t < 32) {
            float dv = 0.f;
            if (t < GN) {
                float d = 1.0f;
                #pragma unroll
                for (int c4 = 0; c4 < 8; ++c4) {
                    f4 v = *(f4*)&S[t * 68 + c4 * 4];
                    d += v.x + v.y + v.z + v.w;
                }
                dv = rsqrtf(d);
            }
            dis[t] = dv;
        }
        LWAIT();

        float dk[8];
        {
            f4 v0 = *(f4*)&dis[quad * 8];
            f4 v1 = *(f4*)&dis[quad * 8 + 4];
            dk[0]=v0.x; dk[1]=v0.y; dk[2]=v0.z; dk[3]=v0.w;
            dk[4]=v1.x; dk[5]=v1.y; dk[6]=v1.z; dk[7]=v1.w;
        }
        Frag aF[2], anF[2];
        #pragma unroll
        for (int mt = 0; mt < 2; ++mt) {
            int m = l15 + 16 * mt;
            float dm = dis[m];
            f4 v0 = *(f4*)&S[m * 68 + quad * 8];
            f4 v1 = *(f4*)&S[m * 68 + quad * 8 + 4];
            float av[8] = {v0.x, v0.y, v0.z, v0.w, v1.x, v1.y, v1.z, v1.w};
            float an[8];
            #pragma unroll
            for (int j = 0; j < 8; ++j) {
                int k = quad * 8 + j;
                an[j] = (av[j] + (m == k ? 1.f : 0.f)) * dm * dk[j];
            }
            #pragma unroll
            for (int p = 0; p < 4; ++p) {
                aF[mt].i[p]  = pkbf(av[2*p], av[2*p+1]);
                anF[mt].i[p] = pkbf(an[2*p], an[2*p+1]);
            }
        }
        LWAIT();

        #pragma unroll
        for (int mt = 0; mt < 2; ++mt)
            #pragma unroll
            for (int nt = 0; nt < 4; ++nt) {
                float bb = b1v[nt];
                f4 c = {bb, bb, bb, bb};
                c = MFMA(aF[mt].s, w1F[nt].s, c);
                int col = nt * 16 + l15;
                #pragma unroll
                for (int r = 0; r < 4; ++r)
                    S[col * 36 + (mt * 16 + quad * 4 + r)] = c[r];
            }
        LWAIT();

        Frag hF[4];
        #pragma unroll
        for (int nt = 0; nt < 4; ++nt) {
            int n = nt * 16 + l15;
            f4 v0 = *(f4*)&S[n * 36 + quad * 8];
            f4 v1 = *(f4*)&S[n * 36 + quad * 8 + 4];
            float vv[8] = {v0.x, v0.y, v0.z, v0.w, v1.x, v1.y, v1.z, v1.w};
            #pragma unroll
            for (int p = 0; p < 4; ++p)
                hF[nt].i[p] = pkbf(vv[2*p] * km[2*p], vv[2*p+1] * km[2*p+1]);
        }
        LWAIT();

        #pragma unroll
        for (int mt = 0; mt < 2; ++mt)
            #pragma unroll
            for (int nt = 0; nt < 4; ++nt) {
                f4 c = {0.f, 0.f, 0.f, 0.f};
                c = MFMA(anF[mt].s, hF[nt].s, c);
                int col = nt * 16 + l15;
                #pragma unroll
                for (int r = 0; r < 4; ++r)
                    S[(mt * 16 + quad * 4 + r) * 68 + col] = fmaxf(c[r], 0.f);
            }
        LWAIT();

        Frag xF[2][2];
        #pragma unroll
        for (int mt = 0; mt < 2; ++mt) {
            int m = l15 + 16 * mt;
            #pragma unroll
            for (int kt = 0; kt < 2; ++kt) {
                f4 v0 = *(f4*)&S[m * 68 + kt * 32 + quad * 8];
                f4 v1 = *(f4*)&S[m * 68 + kt * 32 + quad * 8 + 4];
                xF[mt][kt].i[0] = pkbf(v0.x, v0.y);
                xF[mt][kt].i[1] = pkbf(v0.z, v0.w);
                xF[mt][kt].i[2] = pkbf(v1.x, v1.y);
                xF[mt][kt].i[3] = pkbf(v1.z, v1.w);
            }
        }
        LWAIT();

        #pragma unroll
        for (int mt = 0; mt < 2; ++mt)
            #pragma unroll
            for (int nt = 0; nt < 4; ++nt) {
                float bb = b2v[nt];
                f4 c = {bb, bb, bb, bb};
                c = MFMA(xF[mt][0].s, w2F[0][nt].s, c);
                c = MFMA(xF[mt][1].s, w2F[1][nt].s, c);
                int col = nt * 16 + l15;
                #pragma unroll
                for (int r = 0; r < 4; ++r)
                    S[col * 36 + (mt * 16 + quad * 4 + r)] = c[r];
            }
        LWAIT();

        Frag hG[4];
        #pragma unroll
        for (int nt = 0; nt < 4; ++nt) {
            int n = nt * 16 + l15;
            f4 v0 = *(f4*)&S[n * 36 + quad * 8];
            f4 v1 = *(f4*)&S[n * 36 + quad * 8 + 4];
            float vv[8] = {v0.x, v0.y, v0.z, v0.w, v1.x, v1.y, v1.z, v1.w};
            #pragma unroll
            for (int p = 0; p < 4; ++p)
                hG[nt].i[p] = pkbf(vv[2*p] * km[2*p], vv[2*p+1] * km[2*p+1]);
        }

        float cs[4];
        #pragma unroll
        for (int nt = 0; nt < 4; ++nt) cs[nt] = 0.f;
        #pragma unroll
        for (int mt = 0; mt < 2; ++mt)
            #pragma unroll
            for (int nt = 0; nt < 4; ++nt) {
                f4 c = {0.f, 0.f, 0.f, 0.f};
                c = MFMA(anF[mt].s, hG[nt].s, c);
                if (mt == 0) {
                    cs[nt] += fmaxf(c[0], 0.f) + fmaxf(c[1], 0.f)
                            + fmaxf(c[2], 0.f) + fmaxf(c[3], 0.f);
                } else if (quad == 0) {
                    cs[nt] += fmaxf(c[0], 0.f) + fmaxf(c[1], 0.f) + fmaxf(c[2], 0.f);
                }
            }
        #pragma unroll
        for (int nt = 0; nt < 4; ++nt)
            ps[quad * 64 + nt * 16 + l15] = cs[nt];
        LWAIT();
        float tot = ps[t] + ps[64 + t] + ps[128 + t] + ps[192 + t];
        float mf = (float)mask[g];
        float v = tot * (1.f / 19.f) * mf;
        emb[(size_t)g * 64 + t] = (u16)(unsigned)pkbf(v, v);  // low16 = bf16RNE(v)
        LWAIT();
    }
}

// read single-bf16 h B-fragments straight from LDS (zero VALU)
__device__ __forceinline__ void read_h1(const u16* __restrict__ hs,
                                        int off, Frag* __restrict__ BH)
{
    #pragma unroll
    for (int kt = 0; kt < 2; ++kt) {
        int4 vh = *(const int4*)&hs[off + kt * 32];
        BH[kt].i[0] = vh.x; BH[kt].i[1] = vh.y;
        BH[kt].i[2] = vh.z; BH[kt].i[3] = vh.w;
    }
}

// ---------------------------------------------------------------------------
// Kernel B v8: R5 structure + TWO batch groups PER WAVE.
// R6 post-mortem: waves_per_eu(4,4) halved the register budget to 128 ->
// weights spilled to scratch (VGPR=64, WRITE_SIZE 1346KB = spill-to-HBM),
// 4.4x regression.  Lesson: extra waves/SIMD destroys the register budget
// that keeps weights resident.  So interleave WITHIN the wave instead:
//   512 threads, 8 waves (waves 0-3 = layer 0, 4-7 = layer 1, lag 1),
//   each wave owns 4 gate-tiles of one layer (16 weight frags, shared!)
//   and processes TWO independent batch-16 groups (A: bb0+l15, B: bb0+16+
//   l15) per step.  The two groups' MFMA chains + activation chains are
//   independent -> they interleave in the issue stream and hide each
//   other's latency (R5 measured ~80% stall).  Incremental cost is only
//   B-state (~+50 regs -> ~180 total), within the 256 budget of
//   waves_per_eu(2,2).  Grid 8 blocks x 32 batches.
// ---------------------------------------------------------------------------
__global__ __launch_bounds__(512) __attribute__((amdgpu_waves_per_eu(2, 2)))
void lstm_mfma(
    const u16*   __restrict__ x,      // (B*T, 64) bf16 = emb
    const int*   __restrict__ mask,   // (B, T)
    const float* __restrict__ Wih0, const float* __restrict__ Whh0,
    const float* __restrict__ bih0, const float* __restrict__ bhh0,
    const float* __restrict__ Wih1, const float* __restrict__ Whh1,
    const float* __restrict__ bih1, const float* __restrict__ bhh1,
    const float* __restrict__ fc1_w, const float* __restrict__ fc1_b,
    const float* __restrict__ fc2_w, const float* __restrict__ fc2_b,
    float* __restrict__ out)          // (B, 2)
{
    __shared__ __attribute__((aligned(16))) u16 h0s[2][2][16 * 72]; // [group][dbuf]
    __shared__ __attribute__((aligned(16))) u16 h1s[2][2][16 * 72];
    __shared__ float hlast[32][68];
    __shared__ float red[1024];
    __shared__ int   li_s[32];

    const int tid  = threadIdx.x;     // 0..511
    const int w    = tid >> 6;        // wave 0..7
    const int grp  = w >> 2;          // 0: layer 0 (waves 0-3), 1: layer 1
    const int wl   = w & 3;           // wave within layer
    const int lane = tid & 63;
    const int l15  = lane & 15;       // batch col within group
    const int quad = lane >> 4;
    const int bb0  = blockIdx.x * 32;

    // zero h1 dbuf[0] for both groups (read as h1(-1)=0 after it=0's barrier)
    for (int i = tid; i < 2 * 16 * 72; i += 512) h1s[i / (16 * 72)][0][i % (16 * 72)] = 0;

    // ---- lastidx per batch row (32 rows) ----
    {
        int b32 = tid >> 4, j = tid & 15;
        int s = 0;
        #pragma unroll
        for (int c = 0; c < 16; ++c)
            s += mask[(bb0 + b32) * TT + j + 16 * c];
        red[tid] = (float)s;
    }
    __syncthreads();
    if (tid < 32) {
        float s = 0.f;
        #pragma unroll
        for (int j = 0; j < 16; ++j) s += red[tid * 16 + j];
        int li = (int)s - 1;
        li_s[tid] = li < 0 ? 0 : (li > TT - 1 ? TT - 1 : li);
    }
    __syncthreads();
    const int liA = li_s[l15];
    const int liB = li_s[16 + l15];

    // ---- this wave's layer weights: 4 gate-tiles, 16 frags (SHARED by
    // both batch groups) ----
    const float* __restrict__ Wx = grp ? Wih1 : Wih0;
    const float* __restrict__ Wh = grp ? Whh1 : Whh0;
    const float* __restrict__ bi = grp ? bih1 : bih0;
    const float* __restrict__ bh = grp ? bhh1 : bhh0;

    Frag Ax[4][2], Ah[4][2];
    f4 biasv[4];
    #pragma unroll
    for (int mt = 0; mt < 4; ++mt) {
        int mg = 4 * wl + mt;
        int orig = (l15 & 3) * 64 + (mg * 4 + (l15 >> 2));
        #pragma unroll
        for (int kt = 0; kt < 2; ++kt)
            #pragma unroll
            for (int p = 0; p < 4; ++p) {
                int k = kt * 32 + quad * 8 + 2 * p;
                Ax[mt][kt].i[p] = pkbf(Wx[orig * 64 + k], Wx[orig * 64 + k + 1]);
                Ah[mt][kt].i[p] = pkbf(Wh[orig * 64 + k], Wh[orig * 64 + k + 1]);
            }
        int uu = mg * 4 + quad;
        #pragma unroll
        for (int r = 0; r < 4; ++r)
            biasv[mt][r] = bi[r * 64 + uu] + bh[r * 64 + uu];
    }
    #pragma unroll
    for (int mt = 0; mt < 4; ++mt) {
        PIN8(Ax[mt][0].s); PIN8(Ax[mt][1].s);
        PIN8(Ah[mt][0].s); PIN8(Ah[mt][1].s);
        PINF(biasv[mt]);
    }

    // unit owned by (mt, quad): 16*wl + 4*mt + quad
    const int ubase = 16 * wl + quad;
    const int hoff = l15 * 72 + quad * 8;   // B-frag read base

    // ---- state: two groups ----
    Frag BH0A[2], BH1A[2], BXA[2], BH0B[2], BH1B[2], BXB[2];
    #pragma unroll
    for (int kt = 0; kt < 2; ++kt)
        #pragma unroll
        for (int p = 0; p < 4; ++p) {
            BXA[kt].i[p] = 0; BH0A[kt].i[p] = 0; BH1A[kt].i[p] = 0;
            BXB[kt].i[p] = 0; BH0B[kt].i[p] = 0; BH1B[kt].i[p] = 0;
        }
    float cstA[4] = {0.f, 0.f, 0.f, 0.f}, cstB[4] = {0.f, 0.f, 0.f, 0.f};
    float hlvA[4] = {0.f, 0.f, 0.f, 0.f}, hlvB[4] = {0.f, 0.f, 0.f, 0.f};

    const u16* __restrict__ xbA = x + (size_t)(bb0 + l15) * TT * 64;
    const u16* __restrict__ xbB = x + (size_t)(bb0 + 16 + l15) * TT * 64;
    if (grp == 0) {
        BXA[0] = *(const Frag*)&xbA[quad * 8];
        BXA[1] = *(const Frag*)&xbA[32 + quad * 8];
        BXB[0] = *(const Frag*)&xbB[quad * 8];
        BXB[1] = *(const Frag*)&xbB[32 + quad * 8];
    }

    // iteration it: layer 0 does step it; layer 1 does step it-1.
    #pragma unroll 1
    for (int it = 0; it <= TT; ++it) {
        const int cur = it & 1;
        f4 gA[4], gB[4];
        bool act = false;

        if (grp == 0) {
            if (it < TT) {
                act = true;
                Frag bxA0 = BXA[0], bxA1 = BXA[1];
                Frag bxB0 = BXB[0], bxB1 = BXB[1];
                int tn = it + 1 < TT ? it + 1 : TT - 1;
                BXA[0] = *(const Frag*)&xbA[(size_t)tn * 64 + quad * 8];
                BXA[1] = *(const Frag*)&xbA[(size_t)tn * 64 + 32 + quad * 8];
                BXB[0] = *(const Frag*)&xbB[(size_t)tn * 64 + quad * 8];
                BXB[1] = *(const Frag*)&xbB[(size_t)tn * 64 + 32 + quad * 8];

                // two independent chain sets (A,B) interleave in issue
                #pragma unroll
                for (int mt = 0; mt < 4; ++mt) {
                    f4 ca = biasv[mt];
                    ca = MFMA(Ax[mt][0].s, bxA0.s,    ca);
                    ca = MFMA(Ah[mt][0].s, BH0A[0].s, ca);
                    f4 cb = {0.f, 0.f, 0.f, 0.f};
                    cb = MFMA(Ax[mt][1].s, bxA1.s,    cb);
                    cb = MFMA(Ah[mt][1].s, BH0A[1].s, cb);
                    gA[mt] = ca + cb;
                    f4 cc = biasv[mt];
                    cc = MFMA(Ax[mt][0].s, bxB0.s,    cc);
                    cc = MFMA(Ah[mt][0].s, BH0B[0].s, cc);
                    f4 cd = {0.f, 0.f, 0.f, 0.f};
                    cd = MFMA(Ax[mt][1].s, bxB1.s,    cd);
                    cd = MFMA(Ah[mt][1].s, BH0B[1].s, cd);
                    gB[mt] = cc + cd;
                }
            }
        } else {
            if (it >= 1) {
                act = true;
                #pragma unroll
                for (int mt = 0; mt < 4; ++mt) {
                    f4 ca = biasv[mt];
                    ca = MFMA(Ax[mt][0].s, BH0A[0].s, ca);
                    ca = MFMA(Ah[mt][0].s, BH1A[0].s, ca);
                    f4 cb = {0.f, 0.f, 0.f, 0.f};
                    cb = MFMA(Ax[mt][1].s, BH0A[1].s, cb);
                    cb = MFMA(Ah[mt][1].s, BH1A[1].s, cb);
                    gA[mt] = ca + cb;
                    f4 cc = biasv[mt];
                    cc = MFMA(Ax[mt][0].s, BH0B[0].s, cc);
                    cc = MFMA(Ah[mt][0].s, BH1B[0].s, cc);
                    f4 cd = {0.f, 0.f, 0.f, 0.f};
                    cd = MFMA(Ax[mt][1].s, BH0B[1].s, cd);
                    cd = MFMA(Ah[mt][1].s, BH1B[1].s, cd);
                    gB[mt] = cc + cd;
                }
            }
        }

        if (act) {
            u16* __restrict__ dA = grp ? &h1s[0][cur][0] : &h0s[0][cur][0];
            u16* __restrict__ dB = grp ? &h1s[1][cur][0] : &h0s[1][cur][0];
            #pragma unroll
            for (int mt = 0; mt < 4; ++mt) {
                // group A
                {
                    f4 gg = gA[mt];
                    float si = sigm(gg[0]), sf = sigm(gg[1]);
                    float tg = tanha(gg[2]), so = sigm(gg[3]);
                    float cc = fmaf(sf, cstA[mt], si * tg);
                    cstA[mt] = cc;
                    float h = so * tanha(cc);
                    if (grp && it - 1 == liA) hlvA[mt] = h;
                    dA[l15 * 72 + ubase + 4 * mt] = (u16)(unsigned)pkbf(h, h);
                }
                // group B
                {
                    f4 gg = gB[mt];
                    float si = sigm(gg[0]), sf = sigm(gg[1]);
                    float tg = tanha(gg[2]), so = sigm(gg[3]);
                    float cc = fmaf(sf, cstB[mt], si * tg);
                    cstB[mt] = cc;
                    float h = so * tanha(cc);
                    if (grp && it - 1 == liB) hlvB[mt] = h;
                    dB[l15 * 72 + ubase + 4 * mt] = (u16)(unsigned)pkbf(h, h);
                }
            }
        }

        WGBAR();   // lgkmcnt(0)+s_barrier; X prefetch stays in flight

        if (it < TT) {
            read_h1(h0s[0][cur], hoff, BH0A);
            read_h1(h0s[1][cur], hoff, BH0B);
            if (grp) {
                read_h1(h1s[0][cur], hoff, BH1A);
                read_h1(h1s[1][cur], hoff, BH1B);
            }
        }
    }

    // ---- head (32 batch rows) ----
    if (grp == 1) {
        #pragma unroll
        for (int mt = 0; mt < 4; ++mt) {
            hlast[l15][ubase + 4 * mt]      = hlvA[mt];
            hlast[16 + l15][ubase + 4 * mt] = hlvB[mt];
        }
    }
    __syncthreads();
    #pragma unroll
    for (int rep = 0; rep < 2; ++rep) {
        int idx = tid + 512 * rep;    // 0..1023 = 32 b x 32 o
        int b = idx >> 5, o = idx & 31;
        float acc = fc1_b[o];
        const float* fw = fc1_w + o * 64;
        #pragma unroll
        for (int j = 0; j < 64; ++j)
            acc = fmaf(hlast[b][j], fw[j], acc);
        red[b * 32 + o] = fmaxf(acc, 0.f);
    }
    __syncthreads();
    if (tid < 64) {
        int b = tid >> 1, o = tid & 1;
        float acc = fc2_b[o];
        #pragma unroll
        for (int j = 0; j < 32; ++j)
            acc = fmaf(fc2_w[o * 32 + j], red[b * 32 + j], acc);
        out[(bb0 + b) * 2 + o] = acc;
    }
}

// ---------------------------------------------------------------------------
extern "C" void kernel_launch(void* const* d_in, const int* in_sizes, int n_in,
                              void* d_out, int out_size, void* d_ws, size_t ws_size,
                              hipStream_t stream)
{
    const float* conn  = (const float*)d_in[0];
    const int*   mask  = (const int*)  d_in[1];
    const float* w1_w  = (const float*)d_in[2];
    const float* w1_b  = (const float*)d_in[3];
    const float* w2_w  = (const float*)d_in[4];
    const float* w2_b  = (const float*)d_in[5];
    const float* Wih0  = (const float*)d_in[6];
    const float* Whh0  = (const float*)d_in[7];
    const float* bih0  = (const float*)d_in[8];
    const float* bhh0  = (const float*)d_in[9];
    const float* Wih1  = (const float*)d_in[10];
    const float* Whh1  = (const float*)d_in[11];
    const float* bih1  = (const float*)d_in[12];
    const float* bhh1  = (const float*)d_in[13];
    const float* fc1_w = (const float*)d_in[14];
    const float* fc1_b = (const float*)d_in[15];
    const float* fc2_w = (const float*)d_in[16];
    const float* fc2_b = (const float*)d_in[17];

    float* out = (float*)d_out;
    u16*   emb = (u16*)d_ws;          // 8.4 MB bf16

    const int num_graphs = BB * TT;

    encoder_mfma<<<8192, 64, 0, stream>>>(
        conn, mask, w1_w, w1_b, w2_w, w2_b, emb, num_graphs);

    lstm_mfma<<<8, 512, 0, stream>>>(
        emb, mask, Wih0, Whh0, bih0, bhh0, Wih1, Whh1, bih1, bhh1,
        fc1_w, fc1_b, fc2_w, fc2_b, out);
}

// Round 9
// 499.795 us; speedup vs baseline: 2.8700x; 1.4781x over previous
//
#include <hip/hip_runtime.h>
#include <hip/hip_bf16.h>
#include <math.h>

#define GN 19            // graph nodes
#define BB 256
#define TT 256

typedef short short8 __attribute__((ext_vector_type(8)));
typedef float f4 __attribute__((ext_vector_type(4)));
typedef unsigned short u16;

union Frag { int i[4]; short8 s; };

// wave-local LDS ordering fence: wait LDS ops, NO vmcnt drain, no barrier.
#define LWAIT() __asm__ volatile("s_waitcnt lgkmcnt(0)" ::: "memory")
// workgroup barrier WITHOUT vmcnt(0) drain: global loads stay in flight.
#define WGBAR() __asm__ volatile("s_waitcnt lgkmcnt(0)\ns_barrier" ::: "memory")
// opaque-register pin
#define PIN8(x) __asm__ volatile("" : "+v"(x))
#define PINF(x) __asm__ volatile("" : "+v"(x))

#define MFMA(a,b,c) __builtin_amdgcn_mfma_f32_16x16x32_bf16(a,b,c,0,0,0)

// packed RNE float pair -> bf16 pair (v_cvt_pk_bf16_f32 on gfx950)
__device__ __forceinline__ int pkbf(float a, float b) {
    __hip_bfloat162 h2 = __float22bfloat162_rn(make_float2(a, b));
    union { __hip_bfloat162 h; int i; } u; u.h = h2; return u.i;
}
__device__ __forceinline__ u16 bf16of(float v) {
    return (u16)(unsigned)pkbf(v, v);
}

__device__ __forceinline__ float fexp2(float x) { return __builtin_amdgcn_exp2f(x); }
__device__ __forceinline__ float frcp(float x)  { return __builtin_amdgcn_rcpf(x); }
__device__ __forceinline__ float sigm(float x)  { return frcp(1.f + fexp2(-1.4426950408889634f * x)); }
__device__ __forceinline__ float tanha(float x) { float e = fexp2(2.8853900817779268f * x); return 1.f - 2.f * frcp(e + 1.f); }

// ---------------------------------------------------------------------------
// Kernel A v2: graph encoder, occupancy-focused restructure.
// Old: 1-wave blocks, ~28 fragment regs (~180 VGPR) -> 2 waves/SIMD; chain
// of 8 serialized LDS round trips per graph can't overlap.  New:
//  - 256-thread / 4-wave blocks, one graph stream per wave (2048 blocks x 4
//    = same 8192 streams; no cross-wave sync after init).
//  - w1/w2 B-frags staged ONCE per block in shared LDS, read per use
//    (-48 VGPR -> ~100; budget via waves_per_eu(2,4), no spill possible).
//  - H1^T / X1 / H2^T stored as bf16 u16 in LDS with RNE pkbf at WRITE time
//    and the k>=19 mask folded into the write -> the hF/xF/hG repacks become
//    pure ds_read_b128 (identical bits to the old pack -> BIT-IDENTICAL
//    output), and the per-wave buffer shrinks 9216B -> 5120B.
//  - A region [32][36] f32 (cols>=32 were never read); ps-reduction replaced
//    by __shfl_xor pair.
// LDS/block = 4x5120 + 12288(w) + 512(dis) ~= 33KB -> 4 blocks/CU
// -> 16 waves/CU (4/SIMD), 2x the old occupancy.
// ---------------------------------------------------------------------------
__global__ __launch_bounds__(256) __attribute__((amdgpu_waves_per_eu(2, 4)))
void encoder_mfma(
    const float* __restrict__ conn,   // (G,19,19)
    const int*   __restrict__ mask,   // (G)
    const float* __restrict__ w1_w,   // (64,19)
    const float* __restrict__ w1_b,   // (64)
    const float* __restrict__ w2_w,   // (64,64)
    const float* __restrict__ w2_b,   // (64)
    u16* __restrict__ emb,            // (G,64) bf16
    int num_graphs)
{
    __shared__ __attribute__((aligned(16))) float SA[4][1280];   // 5120B/wave
    __shared__ __attribute__((aligned(16))) u16  wb[12][64][8];  // w1F(4)+w2F(8)
    __shared__ float dis4[4][32];

    const int tid = threadIdx.x;
    const int tw  = tid >> 6;         // wave 0..3 (graph stream)
    const int t   = tid & 63;         // lane
    const int l15 = t & 15;
    const int quad = t >> 4;

    // ---- stage weight B-frags once per block (wave 0) ----
    if (tw == 0) {
        #pragma unroll
        for (int nt = 0; nt < 4; ++nt) {
            int n = nt * 16 + l15;
            Frag f;
            #pragma unroll
            for (int p = 0; p < 4; ++p) {
                int k0 = quad * 8 + 2 * p, k1 = k0 + 1;
                float a = (k0 < GN) ? w1_w[n * GN + k0] : 0.f;
                float b = (k1 < GN) ? w1_w[n * GN + k1] : 0.f;
                f.i[p] = pkbf(a, b);
            }
            *(int4*)&wb[nt][t][0] = *(int4*)&f;
        }
        #pragma unroll
        for (int kt = 0; kt < 2; ++kt)
            #pragma unroll
            for (int nt = 0; nt < 4; ++nt) {
                int n = nt * 16 + l15;
                Frag f;
                #pragma unroll
                for (int p = 0; p < 4; ++p) {
                    int k = kt * 32 + quad * 8 + 2 * p;
                    f.i[p] = pkbf(w2_w[n * 64 + k], w2_w[n * 64 + k + 1]);
                }
                *(int4*)&wb[4 + kt * 4 + nt][t][0] = *(int4*)&f;
            }
    }
    float b1v[4], b2v[4];
    #pragma unroll
    for (int nt = 0; nt < 4; ++nt) {
        b1v[nt] = w1_b[nt * 16 + l15];
        b2v[nt] = w2_b[nt * 16 + l15];
    }
    __syncthreads();   // wb ready; afterwards waves are fully independent

    float* __restrict__ S   = SA[tw];     // A region: [32][36] f32
    u16*  __restrict__ SH   = (u16*)S;    // H^T regions: [64][40] u16
    u16*  __restrict__ SX   = (u16*)S;    // X1 region: [32][40] u16
    float* __restrict__ dis = dis4[tw];

    int rr[6], cc[6];
    #pragma unroll
    for (int i = 0; i < 6; ++i) {
        int e = t + 64 * i;
        rr[i] = e / GN;
        cc[i] = e - rr[i] * GN;
    }

    float pf[6];
    {
        int g0 = blockIdx.x * 4 + tw;
        const float* Ag = conn + (size_t)g0 * (GN * GN);
        #pragma unroll
        for (int i = 0; i < 6; ++i) {
            int e = t + 64 * i;
            if (e < GN * GN) pf[i] = Ag[e];
        }
    }

    #pragma unroll 1
    for (int g = blockIdx.x * 4 + tw; g < num_graphs; g += gridDim.x * 4) {
        // zero A region [32 rows][cols 0..31], stride 36
        #pragma unroll
        for (int i = 0; i < 4; ++i) {
            int s = t + 64 * i;          // 256 f4 slots
            int row = s >> 3, c4 = s & 7;
            f4 z = {0.f, 0.f, 0.f, 0.f};
            *(f4*)&S[row * 36 + c4 * 4] = z;
        }
        LWAIT();
        #pragma unroll
        for (int i = 0; i < 6; ++i) {
            if (t + 64 * i < GN * GN) S[rr[i] * 36 + cc[i]] = pf[i];
        }
        {
            int gn = g + gridDim.x * 4;
            const float* Ag = conn + (size_t)(gn < num_graphs ? gn : g) * (GN * GN);
            #pragma unroll
            for (int i = 0; i < 6; ++i) {
                int e = t + 64 * i;
                if (e < GN * GN) pf[i] = Ag[e];
            }
        }
        LWAIT();

        if (t < 32) {
            float dv = 0.f;
            if (t < GN) {
                float d = 1.0f;          // self loop
                #pragma unroll
                for (int c4 = 0; c4 < 8; ++c4) {
                    f4 v = *(f4*)&S[t * 36 + c4 * 4];
                    d += v.x + v.y + v.z + v.w;
                }
                dv = rsqrtf(d);
            }
            dis[t] = dv;
        }
        LWAIT();

        float dk[8];
        {
            f4 v0 = *(f4*)&dis[quad * 8];
            f4 v1 = *(f4*)&dis[quad * 8 + 4];
            dk[0]=v0.x; dk[1]=v0.y; dk[2]=v0.z; dk[3]=v0.w;
            dk[4]=v1.x; dk[5]=v1.y; dk[6]=v1.z; dk[7]=v1.w;
        }
        Frag aF[2], anF[2];
        #pragma unroll
        for (int mt = 0; mt < 2; ++mt) {
            int m = l15 + 16 * mt;
            float dm = dis[m];
            f4 v0 = *(f4*)&S[m * 36 + quad * 8];
            f4 v1 = *(f4*)&S[m * 36 + quad * 8 + 4];
            float av[8] = {v0.x, v0.y, v0.z, v0.w, v1.x, v1.y, v1.z, v1.w};
            float an[8];
            #pragma unroll
            for (int j = 0; j < 8; ++j) {
                int k = quad * 8 + j;
                an[j] = (av[j] + (m == k ? 1.f : 0.f)) * dm * dk[j];
            }
            #pragma unroll
            for (int p = 0; p < 4; ++p) {
                aF[mt].i[p]  = pkbf(av[2*p], av[2*p+1]);
                anF[mt].i[p] = pkbf(an[2*p], an[2*p+1]);
            }
        }
        LWAIT();   // A reads done before H1^T overwrites the bytes

        // MFMA1: H1 = A @ W1^T + b1 -> SH bf16, k>=19 zeroed at write
        #pragma unroll
        for (int nt = 0; nt < 4; ++nt) {
            Frag wf; *(int4*)&wf = *(int4*)&wb[nt][t][0];
            int nn = nt * 16 + l15;
            #pragma unroll
            for (int mt = 0; mt < 2; ++mt) {
                float bb = b1v[nt];
                f4 c = {bb, bb, bb, bb};
                c = MFMA(aF[mt].s, wf.s, c);
                #pragma unroll
                for (int r = 0; r < 4; ++r) {
                    int k = mt * 16 + quad * 4 + r;
                    float vv = c[r];
                    if (mt == 1) vv = (quad == 0 && r < 3) ? vv : 0.f;
                    SH[nn * 40 + k] = bf16of(vv);
                }
            }
        }
        LWAIT();

        // hF: pure b128 reads (bits identical to old pkbf(v*km) pack)
        Frag hF[4];
        #pragma unroll
        for (int nt = 0; nt < 4; ++nt)
            *(int4*)&hF[nt] = *(const int4*)&SH[(nt * 16 + l15) * 40 + quad * 8];
        LWAIT();   // H1^T reads done before X1 overwrites

        // MFMA2: X1 = relu(An @ H1) -> SX bf16 row-major (rows>=19 are 0)
        #pragma unroll
        for (int nt = 0; nt < 4; ++nt) {
            int nn = nt * 16 + l15;
            #pragma unroll
            for (int mt = 0; mt < 2; ++mt) {
                f4 c = {0.f, 0.f, 0.f, 0.f};
                c = MFMA(anF[mt].s, hF[nt].s, c);
                #pragma unroll
                for (int r = 0; r < 4; ++r) {
                    int m = mt * 16 + quad * 4 + r;
                    SX[m * 40 + nn] = bf16of(fmaxf(c[r], 0.f));
                }
            }
        }
        LWAIT();

        // xF: pure b128 reads
        Frag xF[2][2];
        #pragma unroll
        for (int mt = 0; mt < 2; ++mt) {
            int m = l15 + 16 * mt;
            #pragma unroll
            for (int kt = 0; kt < 2; ++kt)
                *(int4*)&xF[mt][kt] = *(const int4*)&SX[m * 40 + kt * 32 + quad * 8];
        }
        LWAIT();   // X1 reads done before H2^T overwrites

        // MFMA3: H2 = X1 @ W2^T + b2 -> SH bf16 masked
        #pragma unroll
        for (int nt = 0; nt < 4; ++nt) {
            Frag w20; *(int4*)&w20 = *(int4*)&wb[4 + nt][t][0];
            Frag w21; *(int4*)&w21 = *(int4*)&wb[8 + nt][t][0];
            int nn = nt * 16 + l15;
            #pragma unroll
            for (int mt = 0; mt < 2; ++mt) {
                float bb = b2v[nt];
                f4 c = {bb, bb, bb, bb};
                c = MFMA(xF[mt][0].s, w20.s, c);
                c = MFMA(xF[mt][1].s, w21.s, c);
                #pragma unroll
                for (int r = 0; r < 4; ++r) {
                    int k = mt * 16 + quad * 4 + r;
                    float vv = c[r];
                    if (mt == 1) vv = (quad == 0 && r < 3) ? vv : 0.f;
                    SH[nn * 40 + k] = bf16of(vv);
                }
            }
        }
        LWAIT();

        // MFMA4: X2 = relu(An @ H2); column sums -> emb mean
        float cs[4];
        #pragma unroll
        for (int nt = 0; nt < 4; ++nt) {
            Frag hG; *(int4*)&hG = *(const int4*)&SH[(nt * 16 + l15) * 40 + quad * 8];
            float acc = 0.f;
            #pragma unroll
            for (int mt = 0; mt < 2; ++mt) {
                f4 c = {0.f, 0.f, 0.f, 0.f};
                c = MFMA(anF[mt].s, hG.s, c);
                if (mt == 0) {
                    acc += fmaxf(c[0], 0.f) + fmaxf(c[1], 0.f)
                         + fmaxf(c[2], 0.f) + fmaxf(c[3], 0.f);
                } else if (quad == 0) {
                    acc += fmaxf(c[0], 0.f) + fmaxf(c[1], 0.f) + fmaxf(c[2], 0.f);
                }
            }
            cs[nt] = acc;
        }
        // reduce over quad via shfl (replaces ps LDS round trip)
        #pragma unroll
        for (int nt = 0; nt < 4; ++nt) {
            cs[nt] += __shfl_xor(cs[nt], 16);
            cs[nt] += __shfl_xor(cs[nt], 32);
        }
        float tot = cs[0];
        tot = (quad == 1) ? cs[1] : tot;
        tot = (quad == 2) ? cs[2] : tot;
        tot = (quad == 3) ? cs[3] : tot;
        float mf = (float)mask[g];
        float v = tot * (1.f / 19.f) * mf;
        emb[(size_t)g * 64 + t] = bf16of(v);
        LWAIT();   // SH reads done before next iteration's zero overwrites
    }
}

// read single-bf16 h B-fragments straight from LDS (zero VALU)
__device__ __forceinline__ void read_h1(const u16* __restrict__ hs,
                                        int off, Frag* __restrict__ BH)
{
    #pragma unroll
    for (int kt = 0; kt < 2; ++kt) {
        int4 vh = *(const int4*)&hs[off + kt * 32];
        BH[kt].i[0] = vh.x; BH[kt].i[1] = vh.y;
        BH[kt].i[2] = vh.z; BH[kt].i[3] = vh.w;
    }
}

// ---------------------------------------------------------------------------
// Kernel B: EXACT R5 revert (measured 260us).  R6/R7 falsified both
// co-residency routes: extra waves kill the register budget (R6 spill),
// extra in-wave work scales time linearly (R7: issue-bound, per-active-CU
// VALUBusy ~63%).  R5 is this structure's issue floor.
// ---------------------------------------------------------------------------
__global__ __launch_bounds__(512) __attribute__((amdgpu_waves_per_eu(2, 2)))
void lstm_mfma(
    const u16*   __restrict__ x,      // (B*T, 64) bf16 = emb
    const int*   __restrict__ mask,   // (B, T)
    const float* __restrict__ Wih0, const float* __restrict__ Whh0,
    const float* __restrict__ bih0, const float* __restrict__ bhh0,
    const float* __restrict__ Wih1, const float* __restrict__ Whh1,
    const float* __restrict__ bih1, const float* __restrict__ bhh1,
    const float* __restrict__ fc1_w, const float* __restrict__ fc1_b,
    const float* __restrict__ fc2_w, const float* __restrict__ fc2_b,
    float* __restrict__ out)          // (B, 2)
{
    __shared__ __attribute__((aligned(16))) u16 h0s[2][16 * 72];
    __shared__ __attribute__((aligned(16))) u16 h1s[2][16 * 72];
    __shared__ float hlast[16][68];
    __shared__ float red[512];
    __shared__ int   li_s[16];

    const int tid  = threadIdx.x;     // 0..511
    const int w    = tid >> 6;        // wave 0..7
    const int grp  = w >> 2;          // 0: layer 0 (waves 0-3), 1: layer 1
    const int wl   = w & 3;           // wave within layer
    const int lane = tid & 63;
    const int l15  = lane & 15;       // batch col
    const int quad = lane >> 4;
    const int bb0  = blockIdx.x * 16;

    for (int i = tid; i < 16 * 72; i += 512) h1s[0][i] = 0;

    {
        int b16 = tid >> 5, j = tid & 31;
        int s = 0;
        #pragma unroll
        for (int c8 = 0; c8 < 8; ++c8)
            s += mask[(bb0 + b16) * TT + j + 32 * c8];
        red[tid] = (float)s;
    }
    __syncthreads();
    if (tid < 16) {
        float s = 0.f;
        #pragma unroll
        for (int j = 0; j < 32; ++j) s += red[tid * 32 + j];
        int li = (int)s - 1;
        li_s[tid] = li < 0 ? 0 : (li > TT - 1 ? TT - 1 : li);
    }
    __syncthreads();
    const int li = li_s[l15];

    const float* __restrict__ Wx = grp ? Wih1 : Wih0;
    const float* __restrict__ Wh = grp ? Whh1 : Whh0;
    const float* __restrict__ bi = grp ? bih1 : bih0;
    const float* __restrict__ bh = grp ? bhh1 : bhh0;

    Frag Ax[4][2], Ah[4][2];
    f4 biasv[4];
    #pragma unroll
    for (int mt = 0; mt < 4; ++mt) {
        int mg = 4 * wl + mt;
        int orig = (l15 & 3) * 64 + (mg * 4 + (l15 >> 2));
        #pragma unroll
        for (int kt = 0; kt < 2; ++kt)
            #pragma unroll
            for (int p = 0; p < 4; ++p) {
                int k = kt * 32 + quad * 8 + 2 * p;
                Ax[mt][kt].i[p] = pkbf(Wx[orig * 64 + k], Wx[orig * 64 + k + 1]);
                Ah[mt][kt].i[p] = pkbf(Wh[orig * 64 + k], Wh[orig * 64 + k + 1]);
            }
        int uu = mg * 4 + quad;
        #pragma unroll
        for (int r = 0; r < 4; ++r)
            biasv[mt][r] = bi[r * 64 + uu] + bh[r * 64 + uu];
    }
    #pragma unroll
    for (int mt = 0; mt < 4; ++mt) {
        PIN8(Ax[mt][0].s); PIN8(Ax[mt][1].s);
        PIN8(Ah[mt][0].s); PIN8(Ah[mt][1].s);
        PINF(biasv[mt]);
    }

    const int ubase = 16 * wl + quad;
    const int hoff = l15 * 72 + quad * 8;

    Frag BH0[2], BH1[2], BXn[2];
    #pragma unroll
    for (int kt = 0; kt < 2; ++kt)
        #pragma unroll
        for (int p = 0; p < 4; ++p) {
            BXn[kt].i[p] = 0; BH0[kt].i[p] = 0; BH1[kt].i[p] = 0;
        }
    float cst[4] = {0.f, 0.f, 0.f, 0.f};
    float hlv[4] = {0.f, 0.f, 0.f, 0.f};

    const u16* __restrict__ xb = x + (size_t)(bb0 + l15) * TT * 64;
    if (grp == 0) {
        BXn[0] = *(const Frag*)&xb[quad * 8];
        BXn[1] = *(const Frag*)&xb[32 + quad * 8];
    }

    #pragma unroll 1
    for (int it = 0; it <= TT; ++it) {
        const int cur = it & 1;
        f4 g[4];
        bool act = false;

        if (grp == 0) {
            if (it < TT) {
                act = true;
                Frag bx0 = BXn[0], bx1 = BXn[1];
                int tn = it + 1 < TT ? it + 1 : TT - 1;
                BXn[0] = *(const Frag*)&xb[(size_t)tn * 64 + quad * 8];
                BXn[1] = *(const Frag*)&xb[(size_t)tn * 64 + 32 + quad * 8];

                #pragma unroll
                for (int mt = 0; mt < 4; ++mt) {
                    f4 ca = biasv[mt];
                    ca = MFMA(Ax[mt][0].s, bx0.s,    ca);
                    ca = MFMA(Ah[mt][0].s, BH0[0].s, ca);
                    f4 cb = {0.f, 0.f, 0.f, 0.f};
                    cb = MFMA(Ax[mt][1].s, bx1.s,    cb);
                    cb = MFMA(Ah[mt][1].s, BH0[1].s, cb);
                    g[mt] = ca + cb;
                }
            }
        } else {
            if (it >= 1) {
                act = true;
                #pragma unroll
                for (int mt = 0; mt < 4; ++mt) {
                    f4 ca = biasv[mt];
                    ca = MFMA(Ax[mt][0].s, BH0[0].s, ca);
                    ca = MFMA(Ah[mt][0].s, BH1[0].s, ca);
                    f4 cb = {0.f, 0.f, 0.f, 0.f};
                    cb = MFMA(Ax[mt][1].s, BH0[1].s, cb);
                    cb = MFMA(Ah[mt][1].s, BH1[1].s, cb);
                    g[mt] = ca + cb;
                }
            }
        }

        if (act) {
            u16* __restrict__ dst = grp ? h1s[cur] : h0s[cur];
            #pragma unroll
            for (int mt = 0; mt < 4; ++mt) {
                f4 gg = g[mt];
                float si = sigm(gg[0]), sf = sigm(gg[1]);
                float tg = tanha(gg[2]), so = sigm(gg[3]);
                float cc = fmaf(sf, cst[mt], si * tg);
                cst[mt] = cc;
                float h = so * tanha(cc);
                if (grp && it - 1 == li) hlv[mt] = h;
                dst[l15 * 72 + ubase + 4 * mt] = (u16)(unsigned)pkbf(h, h);
            }
        }

        WGBAR();

        if (it < TT) {
            read_h1(h0s[cur], hoff, BH0);
            if (grp) read_h1(h1s[cur], hoff, BH1);
        }
    }

    if (grp == 1) {
        #pragma unroll
        for (int mt = 0; mt < 4; ++mt)
            hlast[l15][ubase + 4 * mt] = hlv[mt];
    }
    __syncthreads();
    {
        int b = tid >> 5, o = tid & 31;
        float acc = fc1_b[o];
        const float* fw = fc1_w + o * 64;
        #pragma unroll
        for (int j = 0; j < 64; ++j)
            acc = fmaf(hlast[b][j], fw[j], acc);
        red[b * 32 + o] = fmaxf(acc, 0.f);
    }
    __syncthreads();
    if (tid < 32) {
        int b = tid >> 1, o = tid & 1;
        float acc = fc2_b[o];
        #pragma unroll
        for (int j = 0; j < 32; ++j)
            acc = fmaf(fc2_w[o * 32 + j], red[b * 32 + j], acc);
        out[(bb0 + b) * 2 + o] = acc;
    }
}

// ---------------------------------------------------------------------------
extern "C" void kernel_launch(void* const* d_in, const int* in_sizes, int n_in,
                              void* d_out, int out_size, void* d_ws, size_t ws_size,
                              hipStream_t stream)
{
    const float* conn  = (const float*)d_in[0];
    const int*   mask  = (const int*)  d_in[1];
    const float* w1_w  = (const float*)d_in[2];
    const float* w1_b  = (const float*)d_in[3];
    const float* w2_w  = (const float*)d_in[4];
    const float* w2_b  = (const float*)d_in[5];
    const float* Wih0  = (const float*)d_in[6];
    const float* Whh0  = (const float*)d_in[7];
    const float* bih0  = (const float*)d_in[8];
    const float* bhh0  = (const float*)d_in[9];
    const float* Wih1  = (const float*)d_in[10];
    const float* Whh1  = (const float*)d_in[11];
    const float* bih1  = (const float*)d_in[12];
    const float* bhh1  = (const float*)d_in[13];
    const float* fc1_w = (const float*)d_in[14];
    const float* fc1_b = (const float*)d_in[15];
    const float* fc2_w = (const float*)d_in[16];
    const float* fc2_b = (const float*)d_in[17];

    float* out = (float*)d_out;
    u16*   emb = (u16*)d_ws;          // 8.4 MB bf16

    const int num_graphs = BB * TT;

    encoder_mfma<<<2048, 256, 0, stream>>>(
        conn, mask, w1_w, w1_b, w2_w, w2_b, emb, num_graphs);

    lstm_mfma<<<16, 512, 0, stream>>>(
        emb, mask, Wih0, Whh0, bih0, bhh0, Wih1, Whh1, bih1, bhh1,
        fc1_w, fc1_b, fc2_w, fc2_b, out);
}